// Round 1
// baseline (939.291 us; speedup 1.0000x reference)
//
#include <hip/hip_runtime.h>

#define NN 100000      // nodes
#define NE 400000      // edges per direction
#define NE2 800000
#define C 200          // in/out channels
#define NREL 475       // 2*237 + loop
#define NB 50          // basis
#define KP 224         // K padded to 7*32
#define NTI 13         // 13 n-tiles of 16 -> 208

typedef __attribute__((ext_vector_type(8))) short short8;
typedef __attribute__((ext_vector_type(4))) float f32x4;

// workspace layout (float offsets)
#define W_RELEMB 0L          // 95,000
#define W_LRW    96000L      // 200
#define W_RIN    97000L      // 95,000
#define W_ROUT   193000L     // 95,000
#define W_DIN    289000L     // 100,000  (deg->dinv, in-direction)
#define W_DOUTD  389000L     // 100,000  (deg->dinv, out-direction)
#define W_YIN    489000L     // 20,000,000
#define W_YOUT   20489000L   // 20,000,000
#define W_WT     40489000L   // bf16: 3*208*224 shorts = 69,888 floats

__device__ __forceinline__ short f2bf(float f) {
  unsigned u = __builtin_bit_cast(unsigned, f);
  return (short)((u + 0x7FFFu + ((u >> 16) & 1u)) >> 16);  // RNE
}

// Pre-transpose + bf16-convert the 3 big weight matrices: WT[mat][n][k] = W[k][n], zero-padded
__global__ void k_wt(const float* w_in, const float* w_out, const float* w_loop, short* wt) {
  int i = blockIdx.x * blockDim.x + threadIdx.x;
  if (i >= 3 * 208 * KP) return;
  int m = i / (208 * KP);
  int r = i % (208 * KP);
  int n = r / KP, k = r % KP;
  const float* W = (m == 0) ? w_in : (m == 1) ? w_out : w_loop;
  float v = (n < C && k < C) ? W[k * C + n] : 0.f;
  wt[i] = f2bf(v);
}

// rel_emb = concat(rel_weight @ basis, loop_rel)  (475 x 200, f32)
__global__ void k_relemb(const float* rw, const float* basis, const float* loop_rel, float* re) {
  __shared__ float row[NB];
  int r = blockIdx.x, j = threadIdx.x;
  if (r == NREL - 1) {
    if (j < C) re[(size_t)r * C + j] = loop_rel[j];
    return;
  }
  if (j < NB) row[j] = rw[r * NB + j];
  __syncthreads();
  if (j < C) {
    float a = 0.f;
    #pragma unroll 5
    for (int b = 0; b < NB; b++) a += row[b] * basis[b * C + j];
    re[(size_t)r * C + j] = a;
  }
}

// R_in = rel_emb@w_in, R_out = rel_emb@w_out, out2 = rel_emb@weight_rel, lrw = loop_rel@w_loop (all f32)
__global__ void k_relmats(const float* re, const float* loop_rel,
                          const float* w_in, const float* w_out, const float* wrel, const float* w_loop,
                          float* Rin, float* Rout, float* out2, float* lrw) {
  __shared__ float row[C];
  int b = blockIdx.x, j = threadIdx.x;
  const float* src; const float* W; float* dst;
  if (b < NREL)            { src = re + (size_t)b * C;              W = w_in;   dst = Rin  + (size_t)b * C; }
  else if (b < 2 * NREL)   { src = re + (size_t)(b - NREL) * C;     W = w_out;  dst = Rout + (size_t)(b - NREL) * C; }
  else if (b < 3 * NREL)   { src = re + (size_t)(b - 2 * NREL) * C; W = wrel;   dst = out2 + (size_t)(b - 2 * NREL) * C; }
  else                     { src = loop_rel;                        W = w_loop; dst = lrw; }
  if (j < C) row[j] = src[j];
  __syncthreads();
  if (j < C) {
    float a = 0.f;
    #pragma unroll 4
    for (int k = 0; k < C; k++) a += row[k] * W[k * C + j];
    dst[j] = a;
  }
}

// degree histograms (float counts) per direction
__global__ void k_deg(const int* ei, float* din, float* doutd) {
  int c = blockIdx.x * blockDim.x + threadIdx.x;
  if (c >= NE2) return;
  int head = ei[c];
  if ((unsigned)head < NN)
    atomicAdd((c < NE ? din : doutd) + head, 1.f);
}

// deg -> dinv in place (covers both arrays, contiguous 200000 floats)
__global__ void k_dinv(float* d) {
  int i = blockIdx.x * blockDim.x + threadIdx.x;
  if (i >= 2 * NN) return;
  float v = d[i];
  d[i] = (v > 0.f) ? rsqrtf(v) : 0.f;
}

// Y_in = X@w_in, Y_out = X@w_out, acc(=d_out) = X@w_loop - lrw   via bf16 MFMA
__global__ __launch_bounds__(256) void k_mm(const float* X, const short* wt, const float* lrw,
                                            float* Yin, float* Yout, float* accout) {
  int wave = (blockIdx.x * blockDim.x + threadIdx.x) >> 6;
  if (wave >= NN / 16) return;          // 6250 row-tiles, no __syncthreads below
  int row0 = wave * 16;
  int lane = threadIdx.x & 63;
  int m = lane & 15, kq = lane >> 4;

  for (int mat = 0; mat < 3; mat++) {
    f32x4 acc[NTI];
    #pragma unroll
    for (int t = 0; t < NTI; t++) acc[t] = (f32x4)(0.f);
    const short* wb = wt + (size_t)mat * 208 * KP;

    for (int ks = 0; ks < 7; ks++) {
      int k0 = ks * 32 + kq * 8;
      short8 a = (short8)(short)0;
      if (k0 < C) {  // k0 multiple of 8; k0<=192 -> k0+7<=199 in-bounds
        const float* xp = X + (size_t)(row0 + m) * C + k0;
        f32x4 f0 = *(const f32x4*)(xp);
        f32x4 f1 = *(const f32x4*)(xp + 4);
        a[0] = f2bf(f0[0]); a[1] = f2bf(f0[1]); a[2] = f2bf(f0[2]); a[3] = f2bf(f0[3]);
        a[4] = f2bf(f1[0]); a[5] = f2bf(f1[1]); a[6] = f2bf(f1[2]); a[7] = f2bf(f1[3]);
      }
      #pragma unroll
      for (int t = 0; t < NTI; t++) {
        short8 bfr = *(const short8*)(wb + ((size_t)(t * 16 + m)) * KP + k0);
        acc[t] = __builtin_amdgcn_mfma_f32_16x16x32_bf16(a, bfr, acc[t], 0, 0, 0);
      }
    }

    float* dst = (mat == 0) ? Yin : (mat == 1) ? Yout : accout;
    #pragma unroll
    for (int t = 0; t < NTI; t++) {
      int n = t * 16 + m;
      if (n >= C) continue;
      size_t base = (size_t)(row0 + kq * 4) * C + n;   // D: col = lane&15, row = 4*(lane>>4)+reg
      if (mat == 2) {
        float l = lrw[n];
        dst[base]         = acc[t][0] - l;
        dst[base + C]     = acc[t][1] - l;
        dst[base + 2 * C] = acc[t][2] - l;
        dst[base + 3 * C] = acc[t][3] - l;
      } else {
        dst[base]         = acc[t][0];
        dst[base + C]     = acc[t][1];
        dst[base + 2 * C] = acc[t][2];
        dst[base + 3 * C] = acc[t][3];
      }
    }
  }
}

// one wave per edge: acc[head] += norm * (Y[tail] - R[et])
__global__ __launch_bounds__(256) void k_edges(const int* ei, const int* etype,
                                               const float* Yin, const float* Yout,
                                               const float* Rin, const float* Rout,
                                               const float* dinvIn, const float* dinvOut,
                                               float* acc) {
  int wid = (blockIdx.x * blockDim.x + threadIdx.x) >> 6;
  if (wid >= NE2) return;
  int lane = threadIdx.x & 63;
  int head = ei[wid];
  int tail = ei[NE2 + wid];
  int ty = etype[wid];
  if ((unsigned)head >= NN || (unsigned)tail >= NN || (unsigned)ty >= NREL) return;
  bool isIn = wid < NE;
  const float* dinv = isIn ? dinvIn : dinvOut;
  float norm = dinv[head] * dinv[tail];
  if (norm == 0.f) return;
  const float* ys = (isIn ? Yin : Yout) + (size_t)tail * C;
  const float* rs = (isIn ? Rin : Rout) + (size_t)ty * C;
  float* ap = acc + (size_t)head * C;
  #pragma unroll
  for (int j = lane; j < C; j += 64)
    atomicAdd(ap + j, norm * (ys[j] - rs[j]));
}

// out = tanh(acc/3), in place, vectorized
__global__ void k_tanh(f32x4* out) {
  int i = blockIdx.x * blockDim.x + threadIdx.x;
  if (i >= NN * C / 4) return;
  f32x4 v = out[i];
  v[0] = tanhf(v[0] * (1.f / 3.f));
  v[1] = tanhf(v[1] * (1.f / 3.f));
  v[2] = tanhf(v[2] * (1.f / 3.f));
  v[3] = tanhf(v[3] * (1.f / 3.f));
  out[i] = v;
}

extern "C" void kernel_launch(void* const* d_in, const int* in_sizes, int n_in,
                              void* d_out, int out_size, void* d_ws, size_t ws_size,
                              hipStream_t stream) {
  const float* X        = (const float*)d_in[0];
  const int*   ei       = (const int*)d_in[1];
  const int*   et       = (const int*)d_in[2];
  const float* basis    = (const float*)d_in[3];
  const float* relw     = (const float*)d_in[4];
  const float* wrel     = (const float*)d_in[5];
  const float* loop_rel = (const float*)d_in[6];
  const float* w_in     = (const float*)d_in[7];
  const float* w_out    = (const float*)d_in[8];
  const float* w_loop   = (const float*)d_in[9];

  float* out = (float*)d_out;
  float* ws  = (float*)d_ws;

  float* re    = ws + W_RELEMB;
  float* lrw   = ws + W_LRW;
  float* Rin   = ws + W_RIN;
  float* Rout  = ws + W_ROUT;
  float* din   = ws + W_DIN;
  float* doutd = ws + W_DOUTD;
  float* Yin   = ws + W_YIN;
  float* Yout  = ws + W_YOUT;
  short* wt    = (short*)(ws + W_WT);
  float* out2  = out + (size_t)NN * C;

  hipMemsetAsync(din, 0, 2 * NN * sizeof(float), stream);

  k_wt<<<(3 * 208 * KP + 255) / 256, 256, 0, stream>>>(w_in, w_out, w_loop, wt);
  k_relemb<<<NREL, 256, 0, stream>>>(relw, basis, loop_rel, re);
  k_relmats<<<3 * NREL + 1, 256, 0, stream>>>(re, loop_rel, w_in, w_out, wrel, w_loop,
                                              Rin, Rout, out2, lrw);
  k_deg<<<(NE2 + 255) / 256, 256, 0, stream>>>(ei, din, doutd);
  k_dinv<<<(2 * NN + 255) / 256, 256, 0, stream>>>(din);
  k_mm<<<(NN / 16 + 3) / 4, 256, 0, stream>>>(X, wt, lrw, Yin, Yout, out);
  k_edges<<<NE2 / 4, 256, 0, stream>>>(ei, et, Yin, Yout, Rin, Rout, din, doutd, out);
  k_tanh<<<(NN * C / 4 + 255) / 256, 256, 0, stream>>>((f32x4*)out);
}

// Round 3
// 460.760 us; speedup vs baseline: 2.0386x; 2.0386x over previous
//
#include <hip/hip_runtime.h>

#define NN 100000      // nodes
#define NE 400000      // edges per direction
#define NE2 800000
#define C 200          // channels
#define NREL 475       // 2*237 + loop
#define NB 50          // basis
#define KP 224         // K padded to 7*32
#define NTI 13         // 13 n-tiles of 16 -> 208
#define NSCAN_BLKS ((2 * NN + 255) / 256)   // 782

typedef __attribute__((ext_vector_type(8))) short short8;
typedef __attribute__((ext_vector_type(4))) float f32x4;
typedef __attribute__((ext_vector_type(2))) float f32x2;

// workspace layout (4-byte word offsets)
#define W_RE     0L          // 95,000 f32  rel_emb
#define W_DINV   95104L      // 200,000 f32 (dir*NN + node)
#define W_DEG    295104L     // 200,000 int (degree, later reused as scatter cursor)
#define W_OFFS   495104L     // 200,001 int CSR offsets
#define W_PSUM   695200L     // 1,024 int   scan partials
#define W_BUCKET 696320L     // 800,000 u32 packed (tail<<9 | type)
#define W_AGG    1496320L    // 20,000,000 u32 = [2*NN][100] bf16-pairs
#define W_WT     21496320L   // 69,888 words = 3*208*224 bf16
// total ~86 MB

__device__ __forceinline__ unsigned short f2bf(float f) {
  unsigned u = __builtin_bit_cast(unsigned, f);
  return (unsigned short)((u + 0x7FFFu + ((u >> 16) & 1u)) >> 16);  // RNE
}
__device__ __forceinline__ unsigned pack2(float a, float b) {
  return (unsigned)f2bf(a) | ((unsigned)f2bf(b) << 16);
}

// ---- tiny precompute kernels -------------------------------------------------

// rel_emb = concat(rel_weight @ basis, loop_rel)  (475 x 200 f32)
__global__ void k_relemb(const float* rw, const float* basis, const float* loop_rel, float* re) {
  __shared__ float row[NB];
  int r = blockIdx.x, j = threadIdx.x;
  if (r == NREL - 1) {
    if (j < C) re[(size_t)r * C + j] = loop_rel[j];
    return;
  }
  if (j < NB) row[j] = rw[r * NB + j];
  __syncthreads();
  if (j < C) {
    float a = 0.f;
    #pragma unroll 5
    for (int b = 0; b < NB; b++) a += row[b] * basis[b * C + j];
    re[(size_t)r * C + j] = a;
  }
}

// out2 = rel_emb @ weight_rel  (475 x 200 f32, full precision)
__global__ void k_out2(const float* re, const float* wrel, float* out2) {
  __shared__ float row[C];
  int b = blockIdx.x, j = threadIdx.x;
  if (j < C) row[j] = re[(size_t)b * C + j];
  __syncthreads();
  if (j < C) {
    float a = 0.f;
    #pragma unroll 4
    for (int k = 0; k < C; k++) a += row[k] * wrel[k * C + j];
    out2[(size_t)b * C + j] = a;
  }
}

// transpose + bf16 the 3 weight mats: wt[mat][n][k] = W[k][n], zero-padded to 208x224
__global__ void k_wt(const float* w_in, const float* w_out, const float* w_loop, short* wt) {
  int i = blockIdx.x * blockDim.x + threadIdx.x;
  if (i >= 3 * 208 * KP) return;
  int m = i / (208 * KP);
  int r = i % (208 * KP);
  int n = r / KP, k = r % KP;
  const float* W = (m == 0) ? w_in : (m == 1) ? w_out : w_loop;
  float v = (n < C && k < C) ? W[k * C + n] : 0.f;
  wt[i] = (short)f2bf(v);
}

// ---- CSR construction --------------------------------------------------------

__global__ void k_deg(const int* ei, int* deg) {
  int c = blockIdx.x * blockDim.x + threadIdx.x;
  if (c >= NE2) return;
  int head = ei[c];
  atomicAdd(deg + (c < NE ? 0 : NN) + head, 1);
}

__global__ void k_dinv(const int* deg, float* dinv) {
  int i = blockIdx.x * blockDim.x + threadIdx.x;
  if (i >= 2 * NN) return;
  int v = deg[i];
  dinv[i] = (v > 0) ? rsqrtf((float)v) : 0.f;
}

// scan step 1: per-block sums of deg
__global__ void k_scan1(const int* deg, int* psum) {
  __shared__ int s[256];
  int t = threadIdx.x, i = blockIdx.x * 256 + t;
  s[t] = (i < 2 * NN) ? deg[i] : 0;
  __syncthreads();
  for (int off = 128; off > 0; off >>= 1) {
    if (t < off) s[t] += s[t + off];
    __syncthreads();
  }
  if (t == 0) psum[blockIdx.x] = s[0];
}

// scan step 2: exclusive scan of partials (single block)
__global__ void k_scan2(int* psum) {
  __shared__ int s[1024];
  int t = threadIdx.x;
  int v = (t < NSCAN_BLKS) ? psum[t] : 0;
  s[t] = v;
  __syncthreads();
  for (int off = 1; off < 1024; off <<= 1) {
    int x = (t >= off) ? s[t - off] : 0;
    __syncthreads();
    s[t] += x;
    __syncthreads();
  }
  if (t < NSCAN_BLKS) psum[t] = s[t] - v;  // exclusive
}

// scan step 3: per-block exclusive scan + block offset -> offs, cursor
__global__ void k_scan3(const int* deg, const int* psum, int* offs, int* cursor) {
  __shared__ int s[256];
  int t = threadIdx.x, i = blockIdx.x * 256 + t;
  int v = (i < 2 * NN) ? deg[i] : 0;
  s[t] = v;
  __syncthreads();
  for (int off = 1; off < 256; off <<= 1) {
    int x = (t >= off) ? s[t - off] : 0;
    __syncthreads();
    s[t] += x;
    __syncthreads();
  }
  if (i < 2 * NN) {
    int o = psum[blockIdx.x] + s[t] - v;
    offs[i] = o;
    cursor[i] = o;
  }
  if (i == 0) offs[2 * NN] = NE2;
}

// scatter packed (tail<<9 | type) into CSR buckets
__global__ void k_scatter(const int* ei, const int* et, int* cursor, unsigned* bucket) {
  int c = blockIdx.x * blockDim.x + threadIdx.x;
  if (c >= NE2) return;
  int head = ei[c];
  int tail = ei[NE2 + c];
  int ty = et[c];
  int pos = atomicAdd(cursor + (c < NE ? 0 : NN) + head, 1);
  bucket[pos] = ((unsigned)tail << 9) | (unsigned)ty;
}

// ---- gather: agg[dir][n] = sum over edges norm*(x[tail] - re[et]), bf16 out --

__global__ __launch_bounds__(256) void k_gather(const unsigned* bucket, const int* offs,
                                                const float* dinv, const float* x,
                                                const float* re, unsigned* agg) {
  int wid = (blockIdx.x * blockDim.x + threadIdx.x) >> 6;
  if (wid >= 2 * NN) return;
  int lane = threadIdx.x & 63;
  int dir = (wid >= NN);
  int s = offs[wid], e = offs[wid + 1];
  float dh = dinv[wid];
  const float* dv = dinv + (dir ? NN : 0);
  int c0 = 2 * lane;        // channels c0, c0+1  (0..127)
  int c1 = 128 + 2 * lane;  // channels c1, c1+1  (lane<36)
  float a0 = 0.f, a1 = 0.f, a2 = 0.f, a3 = 0.f;
  for (int p = s; p < e; ++p) {
    unsigned w = bucket[p];
    int tail = (int)(w >> 9);
    int ty = (int)(w & 511u);
    float nm = dh * dv[tail];
    const float* xp = x + (size_t)tail * C;
    const float* rp = re + (size_t)ty * C;
    f32x2 xv = *(const f32x2*)(xp + c0);
    f32x2 rv = *(const f32x2*)(rp + c0);
    a0 += nm * (xv[0] - rv[0]);
    a1 += nm * (xv[1] - rv[1]);
    if (lane < 36) {
      f32x2 xw = *(const f32x2*)(xp + c1);
      f32x2 rw = *(const f32x2*)(rp + c1);
      a2 += nm * (xw[0] - rw[0]);
      a3 += nm * (xw[1] - rw[1]);
    }
  }
  unsigned* arow = agg + (size_t)wid * 100;
  arow[lane] = pack2(a0, a1);
  if (lane < 36) arow[64 + lane] = pack2(a2, a3);
}

// ---- fused triple matmul + tanh ---------------------------------------------
// out[n] = tanh( (agg_in@Win + agg_out@Wout + (x - loop_rel)@Wloop) / 3 )

__global__ __launch_bounds__(256) void k_mm(const float* x, const float* loop_rel,
                                            const unsigned* agg, const short* wt,
                                            float* out) {
  int wave = (blockIdx.x * blockDim.x + threadIdx.x) >> 6;
  if (wave >= NN / 16) return;
  int row0 = wave * 16;
  int lane = threadIdx.x & 63;
  int m = lane & 15, kq = lane >> 4;

  f32x4 acc[NTI];
  #pragma unroll
  for (int t = 0; t < NTI; t++) acc[t] = (f32x4)(0.f);

  for (int mat = 0; mat < 3; mat++) {
    const short* wb = wt + (size_t)mat * 208 * KP;
    for (int ks = 0; ks < 7; ks++) {
      int k0 = ks * 32 + kq * 8;
      short8 a = (short8)(short)0;
      if (k0 < C) {  // k0 multiple of 8, <=192 -> +7 in bounds
        if (mat < 2) {
          a = *(const short8*)(agg + ((size_t)(mat * NN + row0 + m)) * 100 + (k0 >> 1));
        } else {
          const float* xp = x + (size_t)(row0 + m) * C + k0;
          f32x4 f0 = *(const f32x4*)(xp);
          f32x4 f1 = *(const f32x4*)(xp + 4);
          f32x4 l0 = *(const f32x4*)(loop_rel + k0);
          f32x4 l1 = *(const f32x4*)(loop_rel + k0 + 4);
          a[0] = (short)f2bf(f0[0] - l0[0]); a[1] = (short)f2bf(f0[1] - l0[1]);
          a[2] = (short)f2bf(f0[2] - l0[2]); a[3] = (short)f2bf(f0[3] - l0[3]);
          a[4] = (short)f2bf(f1[0] - l1[0]); a[5] = (short)f2bf(f1[1] - l1[1]);
          a[6] = (short)f2bf(f1[2] - l1[2]); a[7] = (short)f2bf(f1[3] - l1[3]);
        }
      }
      #pragma unroll
      for (int t = 0; t < NTI; t++) {
        short8 bfr = *(const short8*)(wb + ((size_t)(t * 16 + m)) * KP + k0);
        acc[t] = __builtin_amdgcn_mfma_f32_16x16x32_bf16(a, bfr, acc[t], 0, 0, 0);
      }
    }
  }

  #pragma unroll
  for (int t = 0; t < NTI; t++) {
    int n = t * 16 + m;
    if (n >= C) continue;
    size_t base = (size_t)(row0 + kq * 4) * C + n;  // D: col=lane&15, row=4*(lane>>4)+reg
    out[base]         = tanhf(acc[t][0] * (1.f / 3.f));
    out[base + C]     = tanhf(acc[t][1] * (1.f / 3.f));
    out[base + 2 * C] = tanhf(acc[t][2] * (1.f / 3.f));
    out[base + 3 * C] = tanhf(acc[t][3] * (1.f / 3.f));
  }
}

// -----------------------------------------------------------------------------

extern "C" void kernel_launch(void* const* d_in, const int* in_sizes, int n_in,
                              void* d_out, int out_size, void* d_ws, size_t ws_size,
                              hipStream_t stream) {
  const float* X        = (const float*)d_in[0];
  const int*   ei       = (const int*)d_in[1];
  const int*   et       = (const int*)d_in[2];
  const float* basis    = (const float*)d_in[3];
  const float* relw     = (const float*)d_in[4];
  const float* wrel     = (const float*)d_in[5];
  const float* loop_rel = (const float*)d_in[6];
  const float* w_in     = (const float*)d_in[7];
  const float* w_out    = (const float*)d_in[8];
  const float* w_loop   = (const float*)d_in[9];

  float* out = (float*)d_out;
  float* ws  = (float*)d_ws;

  float*    re     = ws + W_RE;
  float*    dinv   = ws + W_DINV;
  int*      deg    = (int*)(ws + W_DEG);     // later reused as cursor
  int*      offs   = (int*)(ws + W_OFFS);
  int*      psum   = (int*)(ws + W_PSUM);
  unsigned* bucket = (unsigned*)(ws + W_BUCKET);
  unsigned* agg    = (unsigned*)(ws + W_AGG);
  short*    wt     = (short*)(ws + W_WT);
  float*    out2   = out + (size_t)NN * C;

  hipMemsetAsync(deg, 0, 2 * NN * sizeof(int), stream);

  k_relemb<<<NREL, 256, 0, stream>>>(relw, basis, loop_rel, re);
  k_out2<<<NREL, 256, 0, stream>>>(re, wrel, out2);
  k_wt<<<(3 * 208 * KP + 255) / 256, 256, 0, stream>>>(w_in, w_out, w_loop, wt);

  k_deg<<<(NE2 + 255) / 256, 256, 0, stream>>>(ei, deg);
  k_dinv<<<(2 * NN + 255) / 256, 256, 0, stream>>>(deg, dinv);
  k_scan1<<<NSCAN_BLKS, 256, 0, stream>>>(deg, psum);
  k_scan2<<<1, 1024, 0, stream>>>(psum);
  k_scan3<<<NSCAN_BLKS, 256, 0, stream>>>(deg, psum, offs, deg /*cursor*/);
  k_scatter<<<(NE2 + 255) / 256, 256, 0, stream>>>(ei, et, deg /*cursor*/, bucket);

  k_gather<<<(2 * NN) / 4, 256, 0, stream>>>(bucket, offs, dinv, X, re, agg);
  k_mm<<<(NN / 16 + 3) / 4, 256, 0, stream>>>(X, loop_rel, agg, wt, out);
}

// Round 7
// 438.432 us; speedup vs baseline: 2.1424x; 1.0509x over previous
//
#include <hip/hip_runtime.h>

#define NN 100000      // nodes
#define NE 400000      // edges per direction
#define NE2 800000
#define C 200          // channels
#define NREL 475       // 2*237 + loop
#define NB 50          // basis
#define KP 224         // K padded to 7*32
#define NTI 13         // 13 n-tiles of 16 -> 208
#define NSCAN_BLKS ((2 * NN + 255) / 256)   // 782

typedef __attribute__((ext_vector_type(8))) short short8;
typedef __attribute__((ext_vector_type(4))) float f32x4;
typedef __attribute__((ext_vector_type(2))) float f32x2;

// workspace layout (u32 word offsets), total ~90 MB
#define W_RE     0L          // 95,000 f32  rel_emb
#define W_DINV   95104L      // 200,000 f32 [dir*NN+node]
#define W_DEG    295104L     // 200,000 int (deg, reused as scatter cursor)
#define W_OFFS   495104L     // 200,001 int CSR offsets
#define W_PSUM   695200L     // 1,024 int
#define W_BUCKET 696320L     // 800,000 u32 packed (tail<<9 | type)
#define W_BNORM  1496320L    // 800,000 f32 per-edge norm (parallel to bucket)
#define W_AGG    2296320L    // 20,000,000 u32 = [2*NN][100] bf16-pairs
#define W_WT     22296320L   // 69,888 words = 3*208*224 bf16

__device__ __forceinline__ unsigned short f2bf(float f) {
  unsigned u = __builtin_bit_cast(unsigned, f);
  return (unsigned short)((u + 0x7FFFu + ((u >> 16) & 1u)) >> 16);  // RNE
}
__device__ __forceinline__ unsigned pack2(float a, float b) {
  return (unsigned)f2bf(a) | ((unsigned)f2bf(b) << 16);
}

// ---- precompute (VERBATIM from R3-passing kernel) ---------------------------

__global__ void k_relemb(const float* rw, const float* basis, const float* loop_rel, float* re) {
  __shared__ float row[NB];
  int r = blockIdx.x, j = threadIdx.x;
  if (r == NREL - 1) {
    if (j < C) re[(size_t)r * C + j] = loop_rel[j];
    return;
  }
  if (j < NB) row[j] = rw[r * NB + j];
  __syncthreads();
  if (j < C) {
    float a = 0.f;
    #pragma unroll 5
    for (int b = 0; b < NB; b++) a += row[b] * basis[b * C + j];
    re[(size_t)r * C + j] = a;
  }
}

__global__ void k_out2(const float* re, const float* wrel, float* out2) {
  __shared__ float row[C];
  int b = blockIdx.x, j = threadIdx.x;
  if (j < C) row[j] = re[(size_t)b * C + j];
  __syncthreads();
  if (j < C) {
    float a = 0.f;
    #pragma unroll 4
    for (int k = 0; k < C; k++) a += row[k] * wrel[k * C + j];
    out2[(size_t)b * C + j] = a;
  }
}

__global__ void k_wt(const float* w_in, const float* w_out, const float* w_loop, short* wt) {
  int i = blockIdx.x * blockDim.x + threadIdx.x;
  if (i >= 3 * 208 * KP) return;
  int m = i / (208 * KP);
  int r = i % (208 * KP);
  int n = r / KP, k = r % KP;
  const float* W = (m == 0) ? w_in : (m == 1) ? w_out : w_loop;
  float v = (n < C && k < C) ? W[k * C + n] : 0.f;
  wt[i] = (short)f2bf(v);
}

// ---- CSR construction (VERBATIM from R3 except k_scatter's bnorm store) -----

__global__ void k_deg(const int* ei, int* deg) {
  int c = blockIdx.x * blockDim.x + threadIdx.x;
  if (c >= NE2) return;
  atomicAdd(deg + (c < NE ? 0 : NN) + ei[c], 1);
}

__global__ void k_dinv(const int* deg, float* dinv) {
  int i = blockIdx.x * blockDim.x + threadIdx.x;
  if (i >= 2 * NN) return;
  int v = deg[i];
  dinv[i] = (v > 0) ? rsqrtf((float)v) : 0.f;
}

__global__ void k_scan1(const int* deg, int* psum) {
  __shared__ int s[256];
  int t = threadIdx.x, i = blockIdx.x * 256 + t;
  s[t] = (i < 2 * NN) ? deg[i] : 0;
  __syncthreads();
  for (int off = 128; off > 0; off >>= 1) {
    if (t < off) s[t] += s[t + off];
    __syncthreads();
  }
  if (t == 0) psum[blockIdx.x] = s[0];
}

__global__ void k_scan2(int* psum) {
  __shared__ int s[1024];
  int t = threadIdx.x;
  int v = (t < NSCAN_BLKS) ? psum[t] : 0;
  s[t] = v;
  __syncthreads();
  for (int off = 1; off < 1024; off <<= 1) {
    int x = (t >= off) ? s[t - off] : 0;
    __syncthreads();
    s[t] += x;
    __syncthreads();
  }
  if (t < NSCAN_BLKS) psum[t] = s[t] - v;  // exclusive
}

__global__ void k_scan3(const int* deg, const int* psum, int* offs, int* cursor) {
  __shared__ int s[256];
  int t = threadIdx.x, i = blockIdx.x * 256 + t;
  int v = (i < 2 * NN) ? deg[i] : 0;
  s[t] = v;
  __syncthreads();
  for (int off = 1; off < 256; off <<= 1) {
    int x = (t >= off) ? s[t - off] : 0;
    __syncthreads();
    s[t] += x;
    __syncthreads();
  }
  if (i < 2 * NN) {
    int o = psum[blockIdx.x] + s[t] - v;
    offs[i] = o;
    cursor[i] = o;
  }
  if (i == 0) offs[2 * NN] = NE2;
}

// SINGLE DELTA vs R3: also store per-edge norm into the parallel bnorm array.
// Bucket format and everything else unchanged.
__global__ void k_scatter(const int* ei, const int* et, const float* dinv,
                          int* cursor, unsigned* bucket, float* bnorm) {
  int c = blockIdx.x * blockDim.x + threadIdx.x;
  if (c >= NE2) return;
  int head = ei[c];
  int tail = ei[NE2 + c];
  int ty = et[c];
  int base = (c < NE) ? 0 : NN;
  float nm = dinv[base + head] * dinv[base + tail];
  int pos = atomicAdd(cursor + base + head, 1);
  bucket[pos] = ((unsigned)tail << 9) | (unsigned)ty;
  bnorm[pos] = nm;
}

// ---- gather (R3 body; norm read from bnorm instead of dinv chain) -----------

__global__ __launch_bounds__(256) void k_gather(const unsigned* bucket, const int* offs,
                                                const float* bnorm, const float* x,
                                                const float* re, unsigned* agg) {
  int wid = (blockIdx.x * blockDim.x + threadIdx.x) >> 6;
  if (wid >= 2 * NN) return;
  int lane = threadIdx.x & 63;
  int s = offs[wid], e = offs[wid + 1];
  int c0 = 2 * lane;        // channels c0, c0+1  (0..127)
  int c1 = 128 + 2 * lane;  // channels c1, c1+1  (lane<36)
  float a0 = 0.f, a1 = 0.f, a2 = 0.f, a3 = 0.f;
  for (int p = s; p < e; ++p) {
    unsigned w = bucket[p];
    int tail = (int)(w >> 9);
    int ty = (int)(w & 511u);
    float nm = bnorm[p];
    const float* xp = x + (size_t)tail * C;
    const float* rp = re + (size_t)ty * C;
    f32x2 xv = *(const f32x2*)(xp + c0);
    f32x2 rv = *(const f32x2*)(rp + c0);
    a0 += nm * (xv[0] - rv[0]);
    a1 += nm * (xv[1] - rv[1]);
    if (lane < 36) {
      f32x2 xw = *(const f32x2*)(xp + c1);
      f32x2 rw = *(const f32x2*)(rp + c1);
      a2 += nm * (xw[0] - rw[0]);
      a3 += nm * (xw[1] - rw[1]);
    }
  }
  unsigned* arow = agg + (size_t)wid * 100;
  arow[lane] = pack2(a0, a1);
  if (lane < 36) arow[64 + lane] = pack2(a2, a3);
}

// ---- fused triple matmul + tanh (VERBATIM from R3-passing kernel) -----------

__global__ __launch_bounds__(256) void k_mm(const float* x, const float* loop_rel,
                                            const unsigned* agg, const short* wt,
                                            float* out) {
  int wave = (blockIdx.x * blockDim.x + threadIdx.x) >> 6;
  if (wave >= NN / 16) return;
  int row0 = wave * 16;
  int lane = threadIdx.x & 63;
  int m = lane & 15, kq = lane >> 4;

  f32x4 acc[NTI];
  #pragma unroll
  for (int t = 0; t < NTI; t++) acc[t] = (f32x4)(0.f);

  for (int mat = 0; mat < 3; mat++) {
    const short* wb = wt + (size_t)mat * 208 * KP;
    for (int ks = 0; ks < 7; ks++) {
      int k0 = ks * 32 + kq * 8;
      short8 a = (short8)(short)0;
      if (k0 < C) {  // k0 multiple of 8, <=192 -> +7 in bounds
        if (mat < 2) {
          a = *(const short8*)(agg + ((size_t)(mat * NN + row0 + m)) * 100 + (k0 >> 1));
        } else {
          const float* xp = x + (size_t)(row0 + m) * C + k0;
          f32x4 f0 = *(const f32x4*)(xp);
          f32x4 f1 = *(const f32x4*)(xp + 4);
          f32x4 l0 = *(const f32x4*)(loop_rel + k0);
          f32x4 l1 = *(const f32x4*)(loop_rel + k0 + 4);
          a[0] = (short)f2bf(f0[0] - l0[0]); a[1] = (short)f2bf(f0[1] - l0[1]);
          a[2] = (short)f2bf(f0[2] - l0[2]); a[3] = (short)f2bf(f0[3] - l0[3]);
          a[4] = (short)f2bf(f1[0] - l1[0]); a[5] = (short)f2bf(f1[1] - l1[1]);
          a[6] = (short)f2bf(f1[2] - l1[2]); a[7] = (short)f2bf(f1[3] - l1[3]);
        }
      }
      #pragma unroll
      for (int t = 0; t < NTI; t++) {
        short8 bfr = *(const short8*)(wb + (size_t)(t * 16 + m) * KP + k0);
        acc[t] = __builtin_amdgcn_mfma_f32_16x16x32_bf16(a, bfr, acc[t], 0, 0, 0);
      }
    }
  }

  #pragma unroll
  for (int t = 0; t < NTI; t++) {
    int n = t * 16 + m;
    if (n >= C) continue;
    size_t base = (size_t)(row0 + kq * 4) * C + n;  // D: col=lane&15, row=4*(lane>>4)+reg
    out[base]         = tanhf(acc[t][0] * (1.f / 3.f));
    out[base + C]     = tanhf(acc[t][1] * (1.f / 3.f));
    out[base + 2 * C] = tanhf(acc[t][2] * (1.f / 3.f));
    out[base + 3 * C] = tanhf(acc[t][3] * (1.f / 3.f));
  }
}

// -----------------------------------------------------------------------------

extern "C" void kernel_launch(void* const* d_in, const int* in_sizes, int n_in,
                              void* d_out, int out_size, void* d_ws, size_t ws_size,
                              hipStream_t stream) {
  const float* X        = (const float*)d_in[0];
  const int*   ei       = (const int*)d_in[1];
  const int*   et       = (const int*)d_in[2];
  const float* basis    = (const float*)d_in[3];
  const float* relw     = (const float*)d_in[4];
  const float* wrel     = (const float*)d_in[5];
  const float* loop_rel = (const float*)d_in[6];
  const float* w_in     = (const float*)d_in[7];
  const float* w_out    = (const float*)d_in[8];
  const float* w_loop   = (const float*)d_in[9];

  float* out = (float*)d_out;
  float* ws  = (float*)d_ws;

  float*    re     = ws + W_RE;
  float*    dinv   = ws + W_DINV;
  int*      deg    = (int*)(ws + W_DEG);     // reused as scatter cursor
  int*      offs   = (int*)(ws + W_OFFS);
  int*      psum   = (int*)(ws + W_PSUM);
  unsigned* bucket = (unsigned*)(ws + W_BUCKET);
  float*    bnorm  = ws + W_BNORM;
  unsigned* agg    = (unsigned*)(ws + W_AGG);
  short*    wt     = (short*)(ws + W_WT);
  float*    out2   = out + (size_t)NN * C;

  hipMemsetAsync(deg, 0, 2 * NN * sizeof(int), stream);

  k_relemb<<<NREL, 256, 0, stream>>>(relw, basis, loop_rel, re);
  k_out2<<<NREL, 256, 0, stream>>>(re, wrel, out2);
  k_wt<<<(3 * 208 * KP + 255) / 256, 256, 0, stream>>>(w_in, w_out, w_loop, wt);

  k_deg<<<(NE2 + 255) / 256, 256, 0, stream>>>(ei, deg);
  k_dinv<<<(2 * NN + 255) / 256, 256, 0, stream>>>(deg, dinv);
  k_scan1<<<NSCAN_BLKS, 256, 0, stream>>>(deg, psum);
  k_scan2<<<1, 1024, 0, stream>>>(psum);
  k_scan3<<<NSCAN_BLKS, 256, 0, stream>>>(deg, psum, offs, deg /*cursor*/);
  k_scatter<<<(NE2 + 255) / 256, 256, 0, stream>>>(ei, et, dinv, deg /*cursor*/, bucket, bnorm);

  k_gather<<<(2 * NN) / 4, 256, 0, stream>>>(bucket, offs, bnorm, X, re, agg);
  k_mm<<<(NN / 16 + 3) / 4, 256, 0, stream>>>(X, loop_rel, agg, wt, out);
}